// Round 6
// baseline (334.113 us; speedup 1.0000x reference)
//
#include <hip/hip_runtime.h>
#include <hip/hip_fp16.h>
#include <cstdint>

// ---------------- CSR build (fully XCD-segmented, R5 lesson) ----------------
// R5 post-mortem: count_rank's 1.6M device-scope atomics on random lines
// thrashed across the 8 non-coherent XCD L2s (WRITE_SIZE 56 MB for a 200 KB
// counter array). Fix: every atomic pass is dst-range segmented; block b
// handles edge chunk b/8 and ONLY dst range b%8 (~6250 nodes -> its counter
// lines stay in one XCD's L2). Edge data is re-read 8x (51 MB streaming,
// L3-resident) -- cheap vs atomic line migration.

#define EPB 2048  // edges per block (256 thr x 8)
#define NSEG 8

__global__ __launch_bounds__(256) void seg_count(const int* __restrict__ dst,
                                                 int* __restrict__ cnt,
                                                 int ne, int seg_size) {
  int range = blockIdx.x % NSEG;
  int chunk = blockIdx.x / NSEG;
  int lo = range * seg_size;
  int hi = lo + seg_size;
  int base = chunk * EPB;
#pragma unroll
  for (int j = 0; j < 8; ++j) {
    int e = base + j * 256 + threadIdx.x;
    if (e < ne) {
      int d = dst[e];
      if (d >= lo && d < hi) atomicAdd(&cnt[d], 1);
    }
  }
}

__global__ void compute_dinv(const int* __restrict__ cnt, float* __restrict__ dinv, int n) {
  int i = blockIdx.x * blockDim.x + threadIdx.x;
  if (i < n) dinv[i] = rsqrtf((float)(cnt[i] + 1));  // +1 self-loop; always > 0
}

__global__ void scan_block(const int* __restrict__ cnt, int* __restrict__ part,
                           int* __restrict__ bsum, int n) {
  __shared__ int s[1024];
  int i = blockIdx.x * 1024 + threadIdx.x;
  int v = (i < n) ? cnt[i] : 0;
  s[threadIdx.x] = v;
  __syncthreads();
  for (int off = 1; off < 1024; off <<= 1) {
    int t = (threadIdx.x >= (unsigned)off) ? s[threadIdx.x - off] : 0;
    __syncthreads();
    s[threadIdx.x] += t;
    __syncthreads();
  }
  if (i < n) part[i] = s[threadIdx.x] - v;           // exclusive within block
  if (threadIdx.x == 1023) bsum[blockIdx.x] = s[1023];
}

__global__ void scan_bsum(int* __restrict__ bsum, int nb) {  // nb <= 64
  int lane = threadIdx.x;
  int v = (lane < nb) ? bsum[lane] : 0;
  int orig = v;
  for (int off = 1; off < 64; off <<= 1) {
    int t = __shfl_up(v, off);
    if (lane >= off) v += t;
  }
  if (lane < nb) bsum[lane] = v - orig;              // exclusive block offsets
}

__global__ void finalize_rowptr(const int* __restrict__ part, const int* __restrict__ bsum,
                                int* __restrict__ row_ptr, int n, int total) {
  int i = blockIdx.x * blockDim.x + threadIdx.x;
  if (i < n) row_ptr[i] = part[i] + bsum[i >> 10];
  if (i == n) row_ptr[n] = total;
}

// Segmented fill: rank comes from XCD-local cursor atomics; col writes land in
// the range's ~800 KB contiguous col slice (local dirty lines, one writeback).

__global__ __launch_bounds__(256) void seg_fill(const int* __restrict__ src,
                                                const int* __restrict__ dst,
                                                int* __restrict__ cursor,
                                                int* __restrict__ col,
                                                int ne, int seg_size) {
  int range = blockIdx.x % NSEG;
  int chunk = blockIdx.x / NSEG;
  int lo = range * seg_size;
  int hi = lo + seg_size;
  int base = chunk * EPB;
#pragma unroll
  for (int j = 0; j < 8; ++j) {
    int e = base + j * 256 + threadIdx.x;
    if (e < ne) {
      int d = dst[e];
      if (d >= lo && d < hi) {
        int pos = atomicAdd(&cursor[d], 1);
        col[pos] = src[e];
      }
    }
  }
}

// ---------------- GEMM (fp32 in, fp16 out) fused with dinv pre-scale ----------------
// fp16 output halves the aggregate's gather bytes (aggregate is fabric-BW
// bound; R4/R5 notes). Accumulation fp32; only the gathered operand rounds.

__global__ __launch_bounds__(256) void gemm_scale_h(const float* __restrict__ in,
                                                    const float* __restrict__ W,
                                                    const float* __restrict__ dinv,
                                                    __half* __restrict__ out, int nrows) {
  __shared__ float ws[16][128];
  __shared__ float xs[64][17];
  int row0 = blockIdx.x * 64;
  int tid = threadIdx.x;
  int rg = tid >> 4;   // 0..15 -> rows rg*4..rg*4+3
  int cg = tid & 15;   // 0..15 -> cols cg*4 & 64+cg*4

  float acc[4][8] = {{0.f}};

  for (int k0 = 0; k0 < 128; k0 += 16) {
    {
      int idx = tid * 8;
      int kk = idx >> 7;
      int f = idx & 127;
      float4 a = *(const float4*)&W[(size_t)(k0 + kk) * 128 + f];
      float4 b = *(const float4*)&W[(size_t)(k0 + kk) * 128 + f + 4];
      *(float4*)&ws[kk][f] = a;
      *(float4*)&ws[kk][f + 4] = b;
    }
    {
      int idx = tid * 4;
      int r = idx >> 4;
      int kk = idx & 15;
      int grow = row0 + r;
      float4 v = make_float4(0.f, 0.f, 0.f, 0.f);
      if (grow < nrows) v = *(const float4*)&in[(size_t)grow * 128 + k0 + kk];
      xs[r][kk] = v.x; xs[r][kk + 1] = v.y; xs[r][kk + 2] = v.z; xs[r][kk + 3] = v.w;
    }
    __syncthreads();
#pragma unroll
    for (int kk = 0; kk < 16; ++kk) {
      float b0[8];
      *(float4*)&b0[0] = *(const float4*)&ws[kk][cg * 4];
      *(float4*)&b0[4] = *(const float4*)&ws[kk][64 + cg * 4];
      float a0 = xs[rg * 4 + 0][kk];
      float a1 = xs[rg * 4 + 1][kk];
      float a2 = xs[rg * 4 + 2][kk];
      float a3 = xs[rg * 4 + 3][kk];
#pragma unroll
      for (int j = 0; j < 8; ++j) {
        acc[0][j] += a0 * b0[j];
        acc[1][j] += a1 * b0[j];
        acc[2][j] += a2 * b0[j];
        acc[3][j] += a3 * b0[j];
      }
    }
    __syncthreads();
  }

#pragma unroll
  for (int r = 0; r < 4; ++r) {
    int grow = row0 + rg * 4 + r;
    if (grow < nrows) {
      float s = dinv[grow];
      __half h[8];
#pragma unroll
      for (int j = 0; j < 8; ++j) h[j] = __float2half_rn(acc[r][j] * s);
      *(uint2*)&out[(size_t)grow * 128 + cg * 4] = *(uint2*)&h[0];
      *(uint2*)&out[(size_t)grow * 128 + 64 + cg * 4] = *(uint2*)&h[4];
    }
  }
}

// ---------------- fp16 row gather helpers ----------------

__device__ inline float4 h4_to_f4(uint2 u) {
  __half2 a = *(__half2*)&u.x;
  __half2 b = *(__half2*)&u.y;
  float2 fa = __half22float2(a);
  float2 fb = __half22float2(b);
  return make_float4(fa.x, fa.y, fb.x, fb.y);
}

// ---------------- Aggregation: 1 node/wave, half-wave = full 256B fp16 row ----------------
// 16 edges / 4 KB outstanding per wave (R3 lesson: maximize bytes in flight).

__global__ __launch_bounds__(256) void aggregate_h(const __half* __restrict__ hsh,
                                                   const int* __restrict__ row_ptr,
                                                   const int* __restrict__ col,
                                                   const float* __restrict__ dinv,
                                                   const float* __restrict__ bias,
                                                   float* __restrict__ out, int n) {
  int node = (blockIdx.x * blockDim.x + threadIdx.x) >> 6;
  if (node >= n) return;
  int lane = threadIdx.x & 63;
  int half_ = lane >> 5;
  int f4 = lane & 31;
  const uint2* rows = (const uint2*)hsh;  // row stride = 32 uint2

  int start = row_ptr[node];
  int end = row_ptr[node + 1];

  float4 acc = make_float4(0.f, 0.f, 0.f, 0.f);
  if (half_ == 0) acc = h4_to_f4(rows[(size_t)node * 32 + f4]);  // self-loop

  int e = start + half_;
  for (; e + 14 < end; e += 16) {
    uint2 u[8];
#pragma unroll
    for (int j = 0; j < 8; ++j) u[j] = rows[(size_t)col[e + 2 * j] * 32 + f4];
#pragma unroll
    for (int j = 0; j < 8; ++j) {
      float4 v = h4_to_f4(u[j]);
      acc.x += v.x; acc.y += v.y; acc.z += v.z; acc.w += v.w;
    }
  }
  for (; e < end; e += 2) {
    float4 v = h4_to_f4(rows[(size_t)col[e] * 32 + f4]);
    acc.x += v.x; acc.y += v.y; acc.z += v.z; acc.w += v.w;
  }

  acc.x += __shfl_xor(acc.x, 32);
  acc.y += __shfl_xor(acc.y, 32);
  acc.z += __shfl_xor(acc.z, 32);
  acc.w += __shfl_xor(acc.w, 32);

  if (half_ == 0) {
    float d = dinv[node];
    float4 b = ((const float4*)bias)[f4];
    float4 o;
    o.x = fmaxf(acc.x * d + b.x, 0.f);
    o.y = fmaxf(acc.y * d + b.y, 0.f);
    o.z = fmaxf(acc.z * d + b.z, 0.f);
    o.w = fmaxf(acc.w * d + b.w, 0.f);
    ((float4*)out)[(size_t)node * 32 + f4] = o;
  }
}

// Layer-2 variant: same gather, fused 128->1 projection with Wc.

__global__ __launch_bounds__(256) void aggregate_dot_h(const __half* __restrict__ hsh,
                                                       const int* __restrict__ row_ptr,
                                                       const int* __restrict__ col,
                                                       const float* __restrict__ dinv,
                                                       const float* __restrict__ bias,
                                                       const float* __restrict__ Wc,
                                                       const float* __restrict__ bc,
                                                       float* __restrict__ out, int n) {
  int node = (blockIdx.x * blockDim.x + threadIdx.x) >> 6;
  if (node >= n) return;
  int lane = threadIdx.x & 63;
  int half_ = lane >> 5;
  int f4 = lane & 31;
  const uint2* rows = (const uint2*)hsh;

  int start = row_ptr[node];
  int end = row_ptr[node + 1];

  float4 acc = make_float4(0.f, 0.f, 0.f, 0.f);
  if (half_ == 0) acc = h4_to_f4(rows[(size_t)node * 32 + f4]);  // self-loop

  int e = start + half_;
  for (; e + 14 < end; e += 16) {
    uint2 u[8];
#pragma unroll
    for (int j = 0; j < 8; ++j) u[j] = rows[(size_t)col[e + 2 * j] * 32 + f4];
#pragma unroll
    for (int j = 0; j < 8; ++j) {
      float4 v = h4_to_f4(u[j]);
      acc.x += v.x; acc.y += v.y; acc.z += v.z; acc.w += v.w;
    }
  }
  for (; e < end; e += 2) {
    float4 v = h4_to_f4(rows[(size_t)col[e] * 32 + f4]);
    acc.x += v.x; acc.y += v.y; acc.z += v.z; acc.w += v.w;
  }

  acc.x += __shfl_xor(acc.x, 32);
  acc.y += __shfl_xor(acc.y, 32);
  acc.z += __shfl_xor(acc.z, 32);
  acc.w += __shfl_xor(acc.w, 32);

  float d = dinv[node];
  float4 b = ((const float4*)bias)[f4];
  float4 w = ((const float4*)Wc)[f4];
  float s = fmaxf(acc.x * d + b.x, 0.f) * w.x
          + fmaxf(acc.y * d + b.y, 0.f) * w.y
          + fmaxf(acc.z * d + b.z, 0.f) * w.z
          + fmaxf(acc.w * d + b.w, 0.f) * w.w;
#pragma unroll
  for (int off = 16; off; off >>= 1) s += __shfl_xor(s, off);
  if (lane == 0) out[node] = s + bc[0];
}

// ---------------- launch ----------------

extern "C" void kernel_launch(void* const* d_in, const int* in_sizes, int n_in,
                              void* d_out, int out_size, void* d_ws, size_t ws_size,
                              hipStream_t stream) {
  const float* x  = (const float*)d_in[0];
  const int* ei   = (const int*)d_in[1];
  const float* W1 = (const float*)d_in[2];
  const float* b1 = (const float*)d_in[3];
  const float* W2 = (const float*)d_in[4];
  const float* b2 = (const float*)d_in[5];
  const float* Wc = (const float*)d_in[6];
  const float* bc = (const float*)d_in[7];
  float* out = (float*)d_out;

  int n  = in_sizes[0] / 128;
  int ne = in_sizes[1] / 2;
  const int* src = ei;
  const int* dst = ei + ne;

  char* p = (char*)d_ws;
  auto alloc = [&](size_t bytes) {
    char* r = p;
    p += (bytes + 255) & ~(size_t)255;
    return r;
  };
  int*    cnt     = (int*)alloc((size_t)n * 4);
  int*    part    = (int*)alloc((size_t)n * 4);
  int*    bsum    = (int*)alloc(64 * 4);
  int*    row_ptr = (int*)alloc((size_t)(n + 1) * 4);
  int*    cursor  = (int*)alloc((size_t)n * 4);
  float*  dinv    = (float*)alloc((size_t)n * 4);
  int*    col     = (int*)alloc((size_t)ne * 4);
  __half* hsh     = (__half*)alloc((size_t)n * 128 * 2);  // fp16 GEMM output
  float*  h1      = (float*)alloc((size_t)n * 128 * 4);   // fp32 layer-1 output

  int seg_size = (n + NSEG - 1) / NSEG;
  int nchunks = (ne + EPB - 1) / EPB;

  hipMemsetAsync(cnt, 0, (size_t)n * 4, stream);
  seg_count<<<nchunks * NSEG, 256, 0, stream>>>(dst, cnt, ne, seg_size);
  compute_dinv<<<(n + 255) / 256, 256, 0, stream>>>(cnt, dinv, n);
  int nsb = (n + 1023) / 1024;  // 49 for n=50000, must be <= 64
  scan_block<<<nsb, 1024, 0, stream>>>(cnt, part, bsum, n);
  scan_bsum<<<1, 64, 0, stream>>>(bsum, nsb);
  finalize_rowptr<<<(n + 1 + 255) / 256, 256, 0, stream>>>(part, bsum, row_ptr, n, ne);
  hipMemcpyAsync(cursor, row_ptr, (size_t)n * 4, hipMemcpyDeviceToDevice, stream);
  seg_fill<<<nchunks * NSEG, 256, 0, stream>>>(src, dst, cursor, col, ne, seg_size);

  int gemm_blocks = (n + 63) / 64;
  int agg_blocks = (n + 3) / 4;  // 4 waves/block, 1 wave/node

  gemm_scale_h<<<gemm_blocks, 256, 0, stream>>>(x, W1, dinv, hsh, n);
  aggregate_h<<<agg_blocks, 256, 0, stream>>>(hsh, row_ptr, col, dinv, b1, h1, n);
  gemm_scale_h<<<gemm_blocks, 256, 0, stream>>>(h1, W2, dinv, hsh, n);  // reuse hsh
  aggregate_dot_h<<<agg_blocks, 256, 0, stream>>>(hsh, row_ptr, col, dinv, b2, Wc, bc, out, n);
}

// Round 7
// 229.220 us; speedup vs baseline: 1.4576x; 1.4576x over previous
//
#include <hip/hip_runtime.h>
#include <hip/hip_fp16.h>
#include <cstdint>

// ---------------- CSR build: atomic-free bucketed counting sort (R7) ----------------
// R6 post-mortem: 1.6M device-scope atomics cost ~50-70us/pass regardless of
// XCD segmentation (resolved at coherence point), and seg_fill's random col
// writes amplified 10x (streaming evictions of partially-dirty lines).
// R7: all per-edge atomics are LDS (workgroup) scope. Bucket = dst>>8
// (256 nodes). hist[bucket][block] -> global scan -> scatter to ebuf grouped
// by bucket -> per-bucket block builds exact CSR slice + dinv in LDS.

#define EPBH 4096   // edges per block in hist/scatter passes (256 thr x 16)
#define DCAP 9216   // LDS staging capacity in bucket_csr (mean ~8163 edges)

__global__ __launch_bounds__(256) void bucket_hist(const int* __restrict__ dst,
                                                   int* __restrict__ hist,
                                                   int ne, int nb, int nbuck) {
  __shared__ int lh[256];
  lh[threadIdx.x] = 0;
  __syncthreads();
  int base = blockIdx.x * EPBH;
#pragma unroll
  for (int j = 0; j < 16; ++j) {
    int e = base + j * 256 + threadIdx.x;
    if (e < ne) {
      int d = __builtin_nontemporal_load(&dst[e]);
      atomicAdd(&lh[d >> 8], 1);
    }
  }
  __syncthreads();
  if (threadIdx.x < nbuck)
    hist[(size_t)threadIdx.x * nb + blockIdx.x] = lh[threadIdx.x];
}

__global__ void scan_block(const int* __restrict__ in, int* __restrict__ part,
                           int* __restrict__ bsum, int n) {
  __shared__ int s[1024];
  int i = blockIdx.x * 1024 + threadIdx.x;
  int v = (i < n) ? in[i] : 0;
  s[threadIdx.x] = v;
  __syncthreads();
  for (int off = 1; off < 1024; off <<= 1) {
    int t = (threadIdx.x >= (unsigned)off) ? s[threadIdx.x - off] : 0;
    __syncthreads();
    s[threadIdx.x] += t;
    __syncthreads();
  }
  if (i < n) part[i] = s[threadIdx.x] - v;           // exclusive within block
  if (threadIdx.x == 1023) bsum[blockIdx.x] = s[1023];
}

__global__ void scan_partials(int* __restrict__ bsum, int nb) {  // nb <= 256
  __shared__ int s[256];
  int v = (threadIdx.x < (unsigned)nb) ? bsum[threadIdx.x] : 0;
  s[threadIdx.x] = v;
  __syncthreads();
  for (int off = 1; off < 256; off <<= 1) {
    int t = (threadIdx.x >= (unsigned)off) ? s[threadIdx.x - off] : 0;
    __syncthreads();
    s[threadIdx.x] += t;
    __syncthreads();
  }
  if (threadIdx.x < (unsigned)nb) bsum[threadIdx.x] = s[threadIdx.x] - v;
}

__global__ void finalize_scan(const int* __restrict__ part, const int* __restrict__ bsum,
                              int* __restrict__ out, int n) {
  int i = blockIdx.x * blockDim.x + threadIdx.x;
  if (i < n) out[i] = part[i] + bsum[i >> 10];
}

__global__ __launch_bounds__(256) void bucket_scatter(const int* __restrict__ src,
                                                      const int* __restrict__ dst,
                                                      const int* __restrict__ scanned,
                                                      uint2* __restrict__ ebuf,
                                                      int ne, int nb, int nbuck) {
  __shared__ int cur[256];
  if (threadIdx.x < nbuck)
    cur[threadIdx.x] = scanned[(size_t)threadIdx.x * nb + blockIdx.x];
  __syncthreads();
  int base = blockIdx.x * EPBH;
#pragma unroll
  for (int j = 0; j < 16; ++j) {
    int e = base + j * 256 + threadIdx.x;
    if (e < ne) {
      int s = __builtin_nontemporal_load(&src[e]);
      int d = __builtin_nontemporal_load(&dst[e]);
      int pos = atomicAdd(&cur[d >> 8], 1);   // LDS-scope
      ebuf[pos] = make_uint2((unsigned)s, (unsigned)d);
    }
  }
}

// One block per bucket: exact CSR slice + dinv, all in LDS.
__global__ __launch_bounds__(256) void bucket_csr(const uint2* __restrict__ ebuf,
                                                  const int* __restrict__ scanned,
                                                  int* __restrict__ row_ptr,
                                                  float* __restrict__ dinv,
                                                  int* __restrict__ col,
                                                  int ne, int nb, int nbuck, int n) {
  __shared__ int lcnt[256];
  __shared__ int lofs[256];
  __shared__ int cur[256];
  __shared__ uint2 sbuf[DCAP];
  int b = blockIdx.x;
  int start = scanned[(size_t)b * nb];
  int end = (b + 1 < nbuck) ? scanned[(size_t)(b + 1) * nb] : ne;
  lcnt[threadIdx.x] = 0;
  __syncthreads();
  for (int k = start + threadIdx.x; k < end; k += 256) {
    uint2 ed = ebuf[k];
    int rel = k - start;
    if (rel < DCAP) sbuf[rel] = ed;
    atomicAdd(&lcnt[ed.y & 255], 1);          // LDS-scope
  }
  __syncthreads();
  int v = lcnt[threadIdx.x];
  lofs[threadIdx.x] = v;
  __syncthreads();
  for (int off = 1; off < 256; off <<= 1) {
    int t = (threadIdx.x >= (unsigned)off) ? lofs[threadIdx.x - off] : 0;
    __syncthreads();
    lofs[threadIdx.x] += t;
    __syncthreads();
  }
  int excl = lofs[threadIdx.x] - v;
  int node = b * 256 + threadIdx.x;
  if (node < n) {
    row_ptr[node] = start + excl;
    dinv[node] = rsqrtf((float)(v + 1));      // +1 self-loop
  }
  cur[threadIdx.x] = start + excl;
  __syncthreads();
  for (int k = start + threadIdx.x; k < end; k += 256) {
    int rel = k - start;
    uint2 ed = (rel < DCAP) ? sbuf[rel] : ebuf[k];
    int pos = atomicAdd(&cur[ed.y & 255], 1); // LDS-scope
    col[pos] = (int)ed.x;
  }
  if (b == nbuck - 1 && threadIdx.x == 0) row_ptr[n] = ne;
}

// ---------------- GEMM (fp32 in, fp16 out) fused with dinv pre-scale ----------------

__global__ __launch_bounds__(256) void gemm_scale_h(const float* __restrict__ in,
                                                    const float* __restrict__ W,
                                                    const float* __restrict__ dinv,
                                                    __half* __restrict__ out, int nrows) {
  __shared__ float ws[16][128];
  __shared__ float xs[64][17];
  int row0 = blockIdx.x * 64;
  int tid = threadIdx.x;
  int rg = tid >> 4;   // 0..15 -> rows rg*4..rg*4+3
  int cg = tid & 15;   // 0..15 -> cols cg*4 & 64+cg*4

  float acc[4][8] = {{0.f}};

  for (int k0 = 0; k0 < 128; k0 += 16) {
    {
      int idx = tid * 8;
      int kk = idx >> 7;
      int f = idx & 127;
      float4 a = *(const float4*)&W[(size_t)(k0 + kk) * 128 + f];
      float4 b = *(const float4*)&W[(size_t)(k0 + kk) * 128 + f + 4];
      *(float4*)&ws[kk][f] = a;
      *(float4*)&ws[kk][f + 4] = b;
    }
    {
      int idx = tid * 4;
      int r = idx >> 4;
      int kk = idx & 15;
      int grow = row0 + r;
      float4 v = make_float4(0.f, 0.f, 0.f, 0.f);
      if (grow < nrows) v = *(const float4*)&in[(size_t)grow * 128 + k0 + kk];
      xs[r][kk] = v.x; xs[r][kk + 1] = v.y; xs[r][kk + 2] = v.z; xs[r][kk + 3] = v.w;
    }
    __syncthreads();
#pragma unroll
    for (int kk = 0; kk < 16; ++kk) {
      float b0[8];
      *(float4*)&b0[0] = *(const float4*)&ws[kk][cg * 4];
      *(float4*)&b0[4] = *(const float4*)&ws[kk][64 + cg * 4];
      float a0 = xs[rg * 4 + 0][kk];
      float a1 = xs[rg * 4 + 1][kk];
      float a2 = xs[rg * 4 + 2][kk];
      float a3 = xs[rg * 4 + 3][kk];
#pragma unroll
      for (int j = 0; j < 8; ++j) {
        acc[0][j] += a0 * b0[j];
        acc[1][j] += a1 * b0[j];
        acc[2][j] += a2 * b0[j];
        acc[3][j] += a3 * b0[j];
      }
    }
    __syncthreads();
  }

#pragma unroll
  for (int r = 0; r < 4; ++r) {
    int grow = row0 + rg * 4 + r;
    if (grow < nrows) {
      float s = dinv[grow];
      __half h[8];
#pragma unroll
      for (int j = 0; j < 8; ++j) h[j] = __float2half_rn(acc[r][j] * s);
      *(uint2*)&out[(size_t)grow * 128 + cg * 4] = *(uint2*)&h[0];
      *(uint2*)&out[(size_t)grow * 128 + 64 + cg * 4] = *(uint2*)&h[4];
    }
  }
}

// ---------------- fp16 row gather helpers ----------------

__device__ inline float4 h4_to_f4(uint2 u) {
  __half2 a = *(__half2*)&u.x;
  __half2 b = *(__half2*)&u.y;
  float2 fa = __half22float2(a);
  float2 fb = __half22float2(b);
  return make_float4(fa.x, fa.y, fb.x, fb.y);
}

// ---------------- Aggregation: 1 node/wave, half-wave = full 256B fp16 row ----------------
// 16 edges / 4 KB outstanding per wave (R3 lesson: maximize bytes in flight).

__global__ __launch_bounds__(256) void aggregate_h(const __half* __restrict__ hsh,
                                                   const int* __restrict__ row_ptr,
                                                   const int* __restrict__ col,
                                                   const float* __restrict__ dinv,
                                                   const float* __restrict__ bias,
                                                   float* __restrict__ out, int n) {
  int node = (blockIdx.x * blockDim.x + threadIdx.x) >> 6;
  if (node >= n) return;
  int lane = threadIdx.x & 63;
  int half_ = lane >> 5;
  int f4 = lane & 31;
  const uint2* rows = (const uint2*)hsh;  // row stride = 32 uint2

  int start = row_ptr[node];
  int end = row_ptr[node + 1];

  float4 acc = make_float4(0.f, 0.f, 0.f, 0.f);
  if (half_ == 0) acc = h4_to_f4(rows[(size_t)node * 32 + f4]);  // self-loop

  int e = start + half_;
  for (; e + 14 < end; e += 16) {
    uint2 u[8];
#pragma unroll
    for (int j = 0; j < 8; ++j) u[j] = rows[(size_t)col[e + 2 * j] * 32 + f4];
#pragma unroll
    for (int j = 0; j < 8; ++j) {
      float4 v = h4_to_f4(u[j]);
      acc.x += v.x; acc.y += v.y; acc.z += v.z; acc.w += v.w;
    }
  }
  for (; e < end; e += 2) {
    float4 v = h4_to_f4(rows[(size_t)col[e] * 32 + f4]);
    acc.x += v.x; acc.y += v.y; acc.z += v.z; acc.w += v.w;
  }

  acc.x += __shfl_xor(acc.x, 32);
  acc.y += __shfl_xor(acc.y, 32);
  acc.z += __shfl_xor(acc.z, 32);
  acc.w += __shfl_xor(acc.w, 32);

  if (half_ == 0) {
    float d = dinv[node];
    float4 b = ((const float4*)bias)[f4];
    float4 o;
    o.x = fmaxf(acc.x * d + b.x, 0.f);
    o.y = fmaxf(acc.y * d + b.y, 0.f);
    o.z = fmaxf(acc.z * d + b.z, 0.f);
    o.w = fmaxf(acc.w * d + b.w, 0.f);
    ((float4*)out)[(size_t)node * 32 + f4] = o;
  }
}

// Layer-2 variant: same gather, fused 128->1 projection with Wc.

__global__ __launch_bounds__(256) void aggregate_dot_h(const __half* __restrict__ hsh,
                                                       const int* __restrict__ row_ptr,
                                                       const int* __restrict__ col,
                                                       const float* __restrict__ dinv,
                                                       const float* __restrict__ bias,
                                                       const float* __restrict__ Wc,
                                                       const float* __restrict__ bc,
                                                       float* __restrict__ out, int n) {
  int node = (blockIdx.x * blockDim.x + threadIdx.x) >> 6;
  if (node >= n) return;
  int lane = threadIdx.x & 63;
  int half_ = lane >> 5;
  int f4 = lane & 31;
  const uint2* rows = (const uint2*)hsh;

  int start = row_ptr[node];
  int end = row_ptr[node + 1];

  float4 acc = make_float4(0.f, 0.f, 0.f, 0.f);
  if (half_ == 0) acc = h4_to_f4(rows[(size_t)node * 32 + f4]);  // self-loop

  int e = start + half_;
  for (; e + 14 < end; e += 16) {
    uint2 u[8];
#pragma unroll
    for (int j = 0; j < 8; ++j) u[j] = rows[(size_t)col[e + 2 * j] * 32 + f4];
#pragma unroll
    for (int j = 0; j < 8; ++j) {
      float4 v = h4_to_f4(u[j]);
      acc.x += v.x; acc.y += v.y; acc.z += v.z; acc.w += v.w;
    }
  }
  for (; e < end; e += 2) {
    float4 v = h4_to_f4(rows[(size_t)col[e] * 32 + f4]);
    acc.x += v.x; acc.y += v.y; acc.z += v.z; acc.w += v.w;
  }

  acc.x += __shfl_xor(acc.x, 32);
  acc.y += __shfl_xor(acc.y, 32);
  acc.z += __shfl_xor(acc.z, 32);
  acc.w += __shfl_xor(acc.w, 32);

  float d = dinv[node];
  float4 b = ((const float4*)bias)[f4];
  float4 w = ((const float4*)Wc)[f4];
  float s = fmaxf(acc.x * d + b.x, 0.f) * w.x
          + fmaxf(acc.y * d + b.y, 0.f) * w.y
          + fmaxf(acc.z * d + b.z, 0.f) * w.z
          + fmaxf(acc.w * d + b.w, 0.f) * w.w;
#pragma unroll
  for (int off = 16; off; off >>= 1) s += __shfl_xor(s, off);
  if (lane == 0) out[node] = s + bc[0];
}

// ---------------- launch ----------------

extern "C" void kernel_launch(void* const* d_in, const int* in_sizes, int n_in,
                              void* d_out, int out_size, void* d_ws, size_t ws_size,
                              hipStream_t stream) {
  const float* x  = (const float*)d_in[0];
  const int* ei   = (const int*)d_in[1];
  const float* W1 = (const float*)d_in[2];
  const float* b1 = (const float*)d_in[3];
  const float* W2 = (const float*)d_in[4];
  const float* b2 = (const float*)d_in[5];
  const float* Wc = (const float*)d_in[6];
  const float* bc = (const float*)d_in[7];
  float* out = (float*)d_out;

  int n  = in_sizes[0] / 128;
  int ne = in_sizes[1] / 2;
  const int* src = ei;
  const int* dst = ei + ne;

  int NBb = (ne + EPBH - 1) / EPBH;      // 391 hist/scatter blocks
  int NBUCK = (n + 255) >> 8;            // 196 buckets (requires n <= 65536)
  int HN = NBUCK * NBb;                  // 76,636 hist entries

  char* p = (char*)d_ws;
  auto alloc = [&](size_t bytes) {
    char* r = p;
    p += (bytes + 255) & ~(size_t)255;
    return r;
  };
  int*    hist    = (int*)alloc((size_t)HN * 4);
  int*    part    = (int*)alloc((size_t)HN * 4);
  int*    bsum    = (int*)alloc(256 * 4);
  int*    row_ptr = (int*)alloc((size_t)(n + 1) * 4);
  float*  dinv    = (float*)alloc((size_t)n * 4);
  int*    col     = (int*)alloc((size_t)ne * 4);
  __half* hsh     = (__half*)alloc((size_t)n * 128 * 2);  // fp16 GEMM output
  float*  h1      = (float*)alloc((size_t)n * 128 * 4);   // fp32 layer-1 output
  // ebuf aliases h1: ebuf (ne*8 = 12.8 MB <= 25.6 MB) is dead after
  // bucket_csr; h1 first written by aggregate_h, strictly later on stream.
  uint2*  ebuf    = (uint2*)h1;

  bucket_hist<<<NBb, 256, 0, stream>>>(dst, hist, ne, NBb, NBUCK);
  int nsb = (HN + 1023) / 1024;          // 75 <= 256
  scan_block<<<nsb, 1024, 0, stream>>>(hist, part, bsum, HN);
  scan_partials<<<1, 256, 0, stream>>>(bsum, nsb);
  finalize_scan<<<(HN + 255) / 256, 256, 0, stream>>>(part, bsum, hist, HN);
  bucket_scatter<<<NBb, 256, 0, stream>>>(src, dst, hist, ebuf, ne, NBb, NBUCK);
  bucket_csr<<<NBUCK, 256, 0, stream>>>(ebuf, hist, row_ptr, dinv, col, ne, NBb, NBUCK, n);

  int gemm_blocks = (n + 63) / 64;
  int agg_blocks = (n + 3) / 4;  // 4 waves/block, 1 wave/node

  gemm_scale_h<<<gemm_blocks, 256, 0, stream>>>(x, W1, dinv, hsh, n);
  aggregate_h<<<agg_blocks, 256, 0, stream>>>(hsh, row_ptr, col, dinv, b1, h1, n);
  gemm_scale_h<<<gemm_blocks, 256, 0, stream>>>(h1, W2, dinv, hsh, n);  // reuse hsh
  aggregate_dot_h<<<agg_blocks, 256, 0, stream>>>(hsh, row_ptr, col, dinv, b2, Wc, bc, out, n);
}